// Round 14
// baseline (200.651 us; speedup 1.0000x reference)
//
#include <hip/hip_runtime.h>

typedef short short4v __attribute__((ext_vector_type(4)));
typedef short short8 __attribute__((ext_vector_type(8)));
typedef float floatx4 __attribute__((ext_vector_type(4)));

// Native bf16 conversion: compiler emits packed v_cvt_pk_bf16_f32 (RTNE).
__device__ __forceinline__ short f2bf(float f) {
    __bf16 h = (__bf16)f;
    return __builtin_bit_cast(short, h);
}

// Convert lora_A (4096x64) and lora_B (64x4096) fp32 -> bf16 in MFMA fragment
// layout for mfma_f32_16x16x32_bf16:
//   lane l holds elem[k][c] with c = l&15, k = 8*(l>>4) + j, j=0..7
__global__ __launch_bounds__(256) void conv_ab(
    const float* __restrict__ A, const float* __restrict__ B,
    short* __restrict__ Abf, short* __restrict__ Bbf) {
    int i = blockIdx.x * 256 + threadIdx.x;   // 0 .. 262143
    int j    = i & 7;
    int lane = (i >> 3) & 63;
    int hi   = i >> 9;                        // A: ks*4+nt ; B: ct*2+ks
    int krow = 8 * (lane >> 4) + j;
    int cc   = lane & 15;
    {   // A fragments
        int ks = hi >> 2, nt = hi & 3;
        Abf[i] = f2bf(A[(size_t)(ks * 32 + krow) * 64 + nt * 16 + cc]);
    }
    {   // B fragments
        int ct = hi >> 1, ks = hi & 1;
        Bbf[i] = f2bf(B[(size_t)(ks * 32 + krow) * 4096 + ct * 16 + cc]);
    }
}

// k1: 8 bf16 split-K partials of t = x @ A (R10 best config: 2-deep rotating
// register pipeline). Grid (1024, 2) x 4 waves; wave w owns rows bx*16..+15,
// ksplit p = by*4+w. Operand-SWAPPED mfma -> lane holds 4 consecutive t-cols
// of ONE row -> direct 8B stores. No LDS, no barriers.
__global__ __launch_bounds__(256, 4) void k1_xA(
    const float* __restrict__ x, const float* __restrict__ tw,
    const short* __restrict__ Abf, short* __restrict__ t8) {
    const int lane = threadIdx.x & 63;
    const int wave = threadIdx.x >> 6;
    const int rowbase = blockIdx.x * 16;
    const int rrow = lane & 15;
    const int kgrp = lane >> 4;
    const int p = blockIdx.y * 4 + wave;      // ksplit 0..7
    const int kbase = p * 512;

    const int row = rowbase + rrow;
    const bool active = (tw[row] != 0.0f);
    const floatx4* xv = (const floatx4*)(x + (size_t)row * 4096 + kbase + kgrp * 8);
    // Abf8[(ksg*4+nt)*64 + lane], ksg = kbase/32 + ks
    const short8* ap = (const short8*)Abf + ((size_t)(kbase >> 5) * 256) + lane;

    floatx4 acc0 = {0,0,0,0}, acc1 = {0,0,0,0}, acc2 = {0,0,0,0}, acc3 = {0,0,0,0};

    floatx4 px[2][2];
    short8  pb[2][4];
    #pragma unroll
    for (int s = 0; s < 2; ++s) {
        px[s][0] = (floatx4){0,0,0,0};
        px[s][1] = (floatx4){0,0,0,0};
        if (active) { px[s][0] = xv[s * 8]; px[s][1] = xv[s * 8 + 1]; }
        pb[s][0] = ap[s * 256 + 0 * 64];
        pb[s][1] = ap[s * 256 + 1 * 64];
        pb[s][2] = ap[s * 256 + 2 * 64];
        pb[s][3] = ap[s * 256 + 3 * 64];
    }

    #pragma unroll
    for (int ks = 0; ks < 16; ++ks) {
        const int s = ks & 1;
        short8 xa;
        xa[0] = f2bf(px[s][0][0]); xa[1] = f2bf(px[s][0][1]);
        xa[2] = f2bf(px[s][0][2]); xa[3] = f2bf(px[s][0][3]);
        xa[4] = f2bf(px[s][1][0]); xa[5] = f2bf(px[s][1][1]);
        xa[6] = f2bf(px[s][1][2]); xa[7] = f2bf(px[s][1][3]);
        short8 b0 = pb[s][0], b1 = pb[s][1], b2 = pb[s][2], b3 = pb[s][3];

        if (ks + 2 < 16) {
            if (active) { px[s][0] = xv[(ks + 2) * 8]; px[s][1] = xv[(ks + 2) * 8 + 1]; }
            pb[s][0] = ap[(ks + 2) * 256 + 0 * 64];
            pb[s][1] = ap[(ks + 2) * 256 + 1 * 64];
            pb[s][2] = ap[(ks + 2) * 256 + 2 * 64];
            pb[s][3] = ap[(ks + 2) * 256 + 3 * 64];
        }

        // swapped: A-matrix fragment as A-operand, x fragment as B-operand.
        // D[m][n] = sum_k A[kbase+k][nt*16+m] * x[rowbase+n][kbase+k]
        acc0 = __builtin_amdgcn_mfma_f32_16x16x32_bf16(b0, xa, acc0, 0, 0, 0);
        acc1 = __builtin_amdgcn_mfma_f32_16x16x32_bf16(b1, xa, acc1, 0, 0, 0);
        acc2 = __builtin_amdgcn_mfma_f32_16x16x32_bf16(b2, xa, acc2, 0, 0, 0);
        acc3 = __builtin_amdgcn_mfma_f32_16x16x32_bf16(b3, xa, acc3, 0, 0, 0);
    }

    // D layout: n = lane&15 (token row), m = 4*kgrp + b (t-col within n-tile)
    // -> lane holds t_p[row][nt*16 + kgrp*4 + 0..3]: contiguous 8B per nt.
    short* tp = t8 + (size_t)p * (16384 * 64) + (size_t)row * 64 + kgrp * 4;
    floatx4 accs[4] = {acc0, acc1, acc2, acc3};
    #pragma unroll
    for (int nt = 0; nt < 4; ++nt) {
        short4v v;
        v[0] = f2bf(accs[nt][0]); v[1] = f2bf(accs[nt][1]);
        v[2] = f2bf(accs[nt][2]); v[3] = f2bf(accs[nt][3]);
        *(short4v*)(tp + nt * 16) = v;
    }
}

// k2: out = ((sum_p t8[p]) @ B) * tw * 2 — the partial-sum is folded INTO the
// MFMA accumulator (C-in accumulates): 8 partials x 2 K-fragments = 16 MFMA
// per n-tile, exact f32 accumulation (replaces the k1_sum kernel AND skips
// the intermediate bf16 rounding of t). 16384 blocks x 4 waves (R9 geometry:
// many small blocks won), LDS-staged row-linear 256B NT stores.
__global__ __launch_bounds__(256, 4) void k2_tB(
    const short* __restrict__ t8, const float* __restrict__ tw,
    const short* __restrict__ Bbf, float* __restrict__ out) {
    __shared__ float tile[16][257];       // +1 float pad (16.4 KB)

    const int lane = threadIdx.x & 63;
    const int wave = threadIdx.x >> 6;
    const int rg = blockIdx.x >> 4;
    const int cs = blockIdx.x & 15;
    const int rowbase = rg * 16;
    const int colblk = cs * 256;
    const int rrow = lane & 15;
    const int kgrp = lane >> 4;
    const int kofs = kgrp * 8;

    // t fragments from all 8 partials (MFMA B-operand after swap):
    // lane holds t8[p][rowbase+rrow][kofs+j] (a0) and [32+kofs+j] (a1).
    const short* tb = t8 + (size_t)(rowbase + rrow) * 64 + kofs;
    short8 a0[8], a1[8];
    #pragma unroll
    for (int p = 0; p < 8; ++p) {
        a0[p] = *(const short8*)(tb + (size_t)p * (16384 * 64));
        a1[p] = *(const short8*)(tb + (size_t)p * (16384 * 64) + 32);
    }

    // B fragments (MFMA A-operand): Bbf8[(ct*2+ks)*64 + lane], ct = col/16
    const short8* bp = (const short8*)Bbf + (size_t)((colblk + wave * 64) >> 4) * 128 + lane;

    const float w = tw[rowbase + rrow] * 2.0f;

    #pragma unroll
    for (int nt = 0; nt < 4; ++nt) {
        short8 b0 = bp[(nt * 2 + 0) * 64];
        short8 b1 = bp[(nt * 2 + 1) * 64];
        floatx4 acc = {0, 0, 0, 0};
        // swapped: lane holds out[rrow][wave*64 + nt*16 + kgrp*4 + 0..3];
        // p-loop folds the split-K partials in the f32 accumulator.
        #pragma unroll
        for (int p = 0; p < 8; ++p) {
            acc = __builtin_amdgcn_mfma_f32_16x16x32_bf16(b0, a0[p], acc, 0, 0, 0);
            acc = __builtin_amdgcn_mfma_f32_16x16x32_bf16(b1, a1[p], acc, 0, 0, 0);
        }
        acc[0] *= w; acc[1] *= w; acc[2] *= w; acc[3] *= w;
        *(floatx4*)&tile[rrow][wave * 64 + nt * 16 + kgrp * 4] = acc;
    }
    __syncthreads();

    // row-linear write-out: wave w -> rows 4w..4w+3; lane l -> row 4w+(l>>4),
    // 16B chunk (l&15)*16B within each 64-float column group q.
    const int orow_i = 4 * wave + (lane >> 4);
    float* orow = out + (size_t)(rowbase + orow_i) * 4096 + colblk;
    #pragma unroll
    for (int q = 0; q < 4; ++q) {
        const int c = q * 64 + rrow * 4;
        floatx4 v = *(const floatx4*)&tile[orow_i][c];
        __builtin_nontemporal_store(v, (floatx4*)(orow + c));
    }
}

extern "C" void kernel_launch(void* const* d_in, const int* in_sizes, int n_in,
                              void* d_out, int out_size, void* d_ws, size_t ws_size,
                              hipStream_t stream) {
    const float* x  = (const float*)d_in[0];   // (8,2048,4096)
    const float* tw = (const float*)d_in[1];   // (8,2048)
    const float* A  = (const float*)d_in[2];   // (4096,64)
    const float* B  = (const float*)d_in[3];   // (64,4096)
    float* out = (float*)d_out;                // (8,2048,4096) fp32

    short* Abf = (short*)d_ws;                 // 512 KB
    short* Bbf = Abf + 262144;                 // 512 KB
    short* t8  = Bbf + 262144;                 // 8 x 16384 x 64 bf16 = 16 MB

    conv_ab<<<1024, 256, 0, stream>>>(A, B, Abf, Bbf);
    k1_xA<<<dim3(1024, 2), 256, 0, stream>>>(x, tw, Abf, t8);
    k2_tB<<<16384, 256, 0, stream>>>(t8, tw, Bbf, out);
}

// Round 15
// 197.514 us; speedup vs baseline: 1.0159x; 1.0159x over previous
//
#include <hip/hip_runtime.h>

typedef short short4v __attribute__((ext_vector_type(4)));
typedef short short8 __attribute__((ext_vector_type(8)));
typedef float floatx4 __attribute__((ext_vector_type(4)));

// Native bf16 conversion: compiler emits packed v_cvt_pk_bf16_f32 (RTNE).
__device__ __forceinline__ short f2bf(float f) {
    __bf16 h = (__bf16)f;
    return __builtin_bit_cast(short, h);
}

// Convert lora_A (4096x64) and lora_B (64x4096) fp32 -> bf16 in MFMA fragment
// layout for mfma_f32_16x16x32_bf16:
//   lane l holds elem[k][c] with c = l&15, k = 8*(l>>4) + j, j=0..7
__global__ __launch_bounds__(256) void conv_ab(
    const float* __restrict__ A, const float* __restrict__ B,
    short* __restrict__ Abf, short* __restrict__ Bbf) {
    int i = blockIdx.x * 256 + threadIdx.x;   // 0 .. 262143
    int j    = i & 7;
    int lane = (i >> 3) & 63;
    int hi   = i >> 9;                        // A: ks*4+nt ; B: ct*2+ks
    int krow = 8 * (lane >> 4) + j;
    int cc   = lane & 15;
    {   // A fragments
        int ks = hi >> 2, nt = hi & 3;
        Abf[i] = f2bf(A[(size_t)(ks * 32 + krow) * 64 + nt * 16 + cc]);
    }
    {   // B fragments
        int ct = hi >> 1, ks = hi & 1;
        Bbf[i] = f2bf(B[(size_t)(ks * 32 + krow) * 4096 + ct * 16 + cc]);
    }
}

// k1: t (f32, 16384x64) += split-K partials of x @ A via unsafeAtomicAdd
// (native global_atomic_add_f32; 8 adds/element total — negligible contention).
// R10's winning body: grid (1024, 2) x 4 waves; wave w owns rows bx*16..+15,
// ksplit p = by*4+w (K-slice 512, 16 iters, 2-deep rotating register pipeline).
// Operand-SWAPPED mfma -> lane holds 4 consecutive t-cols of ONE row.
// No LDS, no barriers. t must be zeroed before launch (memset on stream).
__global__ __launch_bounds__(256, 4) void k1_xA(
    const float* __restrict__ x, const float* __restrict__ tw,
    const short* __restrict__ Abf, float* __restrict__ t) {
    const int lane = threadIdx.x & 63;
    const int wave = threadIdx.x >> 6;
    const int rowbase = blockIdx.x * 16;
    const int rrow = lane & 15;
    const int kgrp = lane >> 4;
    const int p = blockIdx.y * 4 + wave;      // ksplit 0..7
    const int kbase = p * 512;

    const int row = rowbase + rrow;
    const bool active = (tw[row] != 0.0f);
    const floatx4* xv = (const floatx4*)(x + (size_t)row * 4096 + kbase + kgrp * 8);
    // Abf8[(ksg*4+nt)*64 + lane], ksg = kbase/32 + ks
    const short8* ap = (const short8*)Abf + ((size_t)(kbase >> 5) * 256) + lane;

    floatx4 acc0 = {0,0,0,0}, acc1 = {0,0,0,0}, acc2 = {0,0,0,0}, acc3 = {0,0,0,0};

    floatx4 px[2][2];
    short8  pb[2][4];
    #pragma unroll
    for (int s = 0; s < 2; ++s) {
        px[s][0] = (floatx4){0,0,0,0};
        px[s][1] = (floatx4){0,0,0,0};
        if (active) { px[s][0] = xv[s * 8]; px[s][1] = xv[s * 8 + 1]; }
        pb[s][0] = ap[s * 256 + 0 * 64];
        pb[s][1] = ap[s * 256 + 1 * 64];
        pb[s][2] = ap[s * 256 + 2 * 64];
        pb[s][3] = ap[s * 256 + 3 * 64];
    }

    #pragma unroll
    for (int ks = 0; ks < 16; ++ks) {
        const int s = ks & 1;
        short8 xa;
        xa[0] = f2bf(px[s][0][0]); xa[1] = f2bf(px[s][0][1]);
        xa[2] = f2bf(px[s][0][2]); xa[3] = f2bf(px[s][0][3]);
        xa[4] = f2bf(px[s][1][0]); xa[5] = f2bf(px[s][1][1]);
        xa[6] = f2bf(px[s][1][2]); xa[7] = f2bf(px[s][1][3]);
        short8 b0 = pb[s][0], b1 = pb[s][1], b2 = pb[s][2], b3 = pb[s][3];

        if (ks + 2 < 16) {
            if (active) { px[s][0] = xv[(ks + 2) * 8]; px[s][1] = xv[(ks + 2) * 8 + 1]; }
            pb[s][0] = ap[(ks + 2) * 256 + 0 * 64];
            pb[s][1] = ap[(ks + 2) * 256 + 1 * 64];
            pb[s][2] = ap[(ks + 2) * 256 + 2 * 64];
            pb[s][3] = ap[(ks + 2) * 256 + 3 * 64];
        }

        // swapped: A-matrix fragment as A-operand, x fragment as B-operand.
        // D[m][n] = sum_k A[kbase+k][nt*16+m] * x[rowbase+n][kbase+k]
        acc0 = __builtin_amdgcn_mfma_f32_16x16x32_bf16(b0, xa, acc0, 0, 0, 0);
        acc1 = __builtin_amdgcn_mfma_f32_16x16x32_bf16(b1, xa, acc1, 0, 0, 0);
        acc2 = __builtin_amdgcn_mfma_f32_16x16x32_bf16(b2, xa, acc2, 0, 0, 0);
        acc3 = __builtin_amdgcn_mfma_f32_16x16x32_bf16(b3, xa, acc3, 0, 0, 0);
    }

    // D layout: n = lane&15 (token row), m = 4*kgrp + b (t-col within n-tile)
    // -> lane owns t[row][nt*16 + kgrp*4 + 0..3]; f32 atomic-add reduction.
    float* tp = t + (size_t)row * 64 + kgrp * 4;
    floatx4 accs[4] = {acc0, acc1, acc2, acc3};
    #pragma unroll
    for (int nt = 0; nt < 4; ++nt) {
        #pragma unroll
        for (int b = 0; b < 4; ++b)
            unsafeAtomicAdd(tp + nt * 16 + b, accs[nt][b]);
    }
}

// k2: out = (t @ B) * tw * 2, operand-swapped MFMA (chains of 2), LDS-staged
// row-linear 256B NT stores. 16384 blocks x 4 waves (R9 geometry — many small
// blocks won). t is f32 now: fragments converted in-register (8 cvt_pk/lane).
__global__ __launch_bounds__(256, 4) void k2_tB(
    const float* __restrict__ t, const float* __restrict__ tw,
    const short* __restrict__ Bbf, float* __restrict__ out) {
    __shared__ float tile[16][257];       // +1 float pad (16.4 KB)

    const int lane = threadIdx.x & 63;
    const int wave = threadIdx.x >> 6;
    const int rg = blockIdx.x >> 4;
    const int cs = blockIdx.x & 15;
    const int rowbase = rg * 16;
    const int colblk = cs * 256;
    const int rrow = lane & 15;
    const int kgrp = lane >> 4;
    const int kofs = kgrp * 8;

    // t fragment (MFMA B-operand): lane holds t[rowbase+rrow][kofs+j], j=0..7
    // (a0) and [32+kofs+j] (a1) — f32 loads + in-register bf16 convert.
    const float* tp = t + (size_t)(rowbase + rrow) * 64 + kofs;
    floatx4 t00 = *(const floatx4*)tp;
    floatx4 t01 = *(const floatx4*)(tp + 4);
    floatx4 t10 = *(const floatx4*)(tp + 32);
    floatx4 t11 = *(const floatx4*)(tp + 36);
    short8 a0, a1;
    a0[0] = f2bf(t00[0]); a0[1] = f2bf(t00[1]); a0[2] = f2bf(t00[2]); a0[3] = f2bf(t00[3]);
    a0[4] = f2bf(t01[0]); a0[5] = f2bf(t01[1]); a0[6] = f2bf(t01[2]); a0[7] = f2bf(t01[3]);
    a1[0] = f2bf(t10[0]); a1[1] = f2bf(t10[1]); a1[2] = f2bf(t10[2]); a1[3] = f2bf(t10[3]);
    a1[4] = f2bf(t11[0]); a1[5] = f2bf(t11[1]); a1[6] = f2bf(t11[2]); a1[7] = f2bf(t11[3]);

    // B fragments (MFMA A-operand): Bbf8[(ct*2+ks)*64 + lane], ct = col/16
    const short8* bp = (const short8*)Bbf + (size_t)((colblk + wave * 64) >> 4) * 128 + lane;

    const float w = tw[rowbase + rrow] * 2.0f;

    #pragma unroll
    for (int nt = 0; nt < 4; ++nt) {
        short8 b0 = bp[(nt * 2 + 0) * 64];
        short8 b1 = bp[(nt * 2 + 1) * 64];
        floatx4 acc = {0, 0, 0, 0};
        // swapped: lane holds out[rrow][wave*64 + nt*16 + kgrp*4 + 0..3]
        acc = __builtin_amdgcn_mfma_f32_16x16x32_bf16(b0, a0, acc, 0, 0, 0);
        acc = __builtin_amdgcn_mfma_f32_16x16x32_bf16(b1, a1, acc, 0, 0, 0);
        acc[0] *= w; acc[1] *= w; acc[2] *= w; acc[3] *= w;
        *(floatx4*)&tile[rrow][wave * 64 + nt * 16 + kgrp * 4] = acc;
    }
    __syncthreads();

    // row-linear write-out: wave w -> rows 4w..4w+3; lane l -> row 4w+(l>>4),
    // 16B chunk (l&15)*16B within each 64-float column group q.
    const int orow_i = 4 * wave + (lane >> 4);
    float* orow = out + (size_t)(rowbase + orow_i) * 4096 + colblk;
    #pragma unroll
    for (int q = 0; q < 4; ++q) {
        const int c = q * 64 + rrow * 4;
        floatx4 v = *(const floatx4*)&tile[orow_i][c];
        __builtin_nontemporal_store(v, (floatx4*)(orow + c));
    }
}

extern "C" void kernel_launch(void* const* d_in, const int* in_sizes, int n_in,
                              void* d_out, int out_size, void* d_ws, size_t ws_size,
                              hipStream_t stream) {
    const float* x  = (const float*)d_in[0];   // (8,2048,4096)
    const float* tw = (const float*)d_in[1];   // (8,2048)
    const float* A  = (const float*)d_in[2];   // (4096,64)
    const float* B  = (const float*)d_in[3];   // (64,4096)
    float* out = (float*)d_out;                // (8,2048,4096) fp32

    short* Abf = (short*)d_ws;                 // 512 KB
    short* Bbf = Abf + 262144;                 // 512 KB
    float* t   = (float*)(Bbf + 262144);       // 16384 x 64 f32 = 4 MB

    conv_ab<<<1024, 256, 0, stream>>>(A, B, Abf, Bbf);
    hipMemsetAsync(t, 0, (size_t)16384 * 64 * sizeof(float), stream);
    k1_xA<<<dim3(1024, 2), 256, 0, stream>>>(x, tw, Abf, t);
    k2_tB<<<16384, 256, 0, stream>>>(t, tw, Bbf, out);
}

// Round 16
// 92.909 us; speedup vs baseline: 2.1596x; 2.1259x over previous
//
#include <hip/hip_runtime.h>

typedef short short4v __attribute__((ext_vector_type(4)));
typedef short short8 __attribute__((ext_vector_type(8)));
typedef float floatx4 __attribute__((ext_vector_type(4)));

// Native bf16 conversion: compiler emits packed v_cvt_pk_bf16_f32 (RTNE).
__device__ __forceinline__ short f2bf(float f) {
    __bf16 h = (__bf16)f;
    return __builtin_bit_cast(short, h);
}
__device__ __forceinline__ float bf2f(short s) {
    unsigned u = ((unsigned)(unsigned short)s) << 16;
    return __builtin_bit_cast(float, u);
}

// Convert lora_A (4096x64) and lora_B (64x4096) fp32 -> bf16 in MFMA fragment
// layout for mfma_f32_16x16x32_bf16:
//   lane l holds elem[k][c] with c = l&15, k = 8*(l>>4) + j, j=0..7
__global__ __launch_bounds__(256) void conv_ab(
    const float* __restrict__ A, const float* __restrict__ B,
    short* __restrict__ Abf, short* __restrict__ Bbf) {
    int i = blockIdx.x * 256 + threadIdx.x;   // 0 .. 262143
    int j    = i & 7;
    int lane = (i >> 3) & 63;
    int hi   = i >> 9;                        // A: ks*4+nt ; B: ct*2+ks
    int krow = 8 * (lane >> 4) + j;
    int cc   = lane & 15;
    {   // A fragments
        int ks = hi >> 2, nt = hi & 3;
        Abf[i] = f2bf(A[(size_t)(ks * 32 + krow) * 64 + nt * 16 + cc]);
    }
    {   // B fragments
        int ct = hi >> 1, ks = hi & 1;
        Bbf[i] = f2bf(B[(size_t)(ks * 32 + krow) * 4096 + ct * 16 + cc]);
    }
}

// k1: 8 bf16 split-K partials of t = x @ A (R10 best config: 2-deep rotating
// register pipeline). Grid (1024, 2) x 4 waves; wave w owns rows bx*16..+15,
// ksplit p = by*4+w. Operand-SWAPPED mfma -> lane holds 4 consecutive t-cols
// of ONE row -> direct 8B stores. No LDS, no barriers.
__global__ __launch_bounds__(256, 4) void k1_xA(
    const float* __restrict__ x, const float* __restrict__ tw,
    const short* __restrict__ Abf, short* __restrict__ t8) {
    const int lane = threadIdx.x & 63;
    const int wave = threadIdx.x >> 6;
    const int rowbase = blockIdx.x * 16;
    const int rrow = lane & 15;
    const int kgrp = lane >> 4;
    const int p = blockIdx.y * 4 + wave;      // ksplit 0..7
    const int kbase = p * 512;

    const int row = rowbase + rrow;
    const bool active = (tw[row] != 0.0f);
    const floatx4* xv = (const floatx4*)(x + (size_t)row * 4096 + kbase + kgrp * 8);
    // Abf8[(ksg*4+nt)*64 + lane], ksg = kbase/32 + ks
    const short8* ap = (const short8*)Abf + ((size_t)(kbase >> 5) * 256) + lane;

    floatx4 acc0 = {0,0,0,0}, acc1 = {0,0,0,0}, acc2 = {0,0,0,0}, acc3 = {0,0,0,0};

    floatx4 px[2][2];
    short8  pb[2][4];
    #pragma unroll
    for (int s = 0; s < 2; ++s) {
        px[s][0] = (floatx4){0,0,0,0};
        px[s][1] = (floatx4){0,0,0,0};
        if (active) { px[s][0] = xv[s * 8]; px[s][1] = xv[s * 8 + 1]; }
        pb[s][0] = ap[s * 256 + 0 * 64];
        pb[s][1] = ap[s * 256 + 1 * 64];
        pb[s][2] = ap[s * 256 + 2 * 64];
        pb[s][3] = ap[s * 256 + 3 * 64];
    }

    #pragma unroll
    for (int ks = 0; ks < 16; ++ks) {
        const int s = ks & 1;
        short8 xa;
        xa[0] = f2bf(px[s][0][0]); xa[1] = f2bf(px[s][0][1]);
        xa[2] = f2bf(px[s][0][2]); xa[3] = f2bf(px[s][0][3]);
        xa[4] = f2bf(px[s][1][0]); xa[5] = f2bf(px[s][1][1]);
        xa[6] = f2bf(px[s][1][2]); xa[7] = f2bf(px[s][1][3]);
        short8 b0 = pb[s][0], b1 = pb[s][1], b2 = pb[s][2], b3 = pb[s][3];

        if (ks + 2 < 16) {
            if (active) { px[s][0] = xv[(ks + 2) * 8]; px[s][1] = xv[(ks + 2) * 8 + 1]; }
            pb[s][0] = ap[(ks + 2) * 256 + 0 * 64];
            pb[s][1] = ap[(ks + 2) * 256 + 1 * 64];
            pb[s][2] = ap[(ks + 2) * 256 + 2 * 64];
            pb[s][3] = ap[(ks + 2) * 256 + 3 * 64];
        }

        // swapped: A-matrix fragment as A-operand, x fragment as B-operand.
        // D[m][n] = sum_k A[kbase+k][nt*16+m] * x[rowbase+n][kbase+k]
        acc0 = __builtin_amdgcn_mfma_f32_16x16x32_bf16(b0, xa, acc0, 0, 0, 0);
        acc1 = __builtin_amdgcn_mfma_f32_16x16x32_bf16(b1, xa, acc1, 0, 0, 0);
        acc2 = __builtin_amdgcn_mfma_f32_16x16x32_bf16(b2, xa, acc2, 0, 0, 0);
        acc3 = __builtin_amdgcn_mfma_f32_16x16x32_bf16(b3, xa, acc3, 0, 0, 0);
    }

    // D layout: n = lane&15 (token row), m = 4*kgrp + b (t-col within n-tile)
    // -> lane holds t_p[row][nt*16 + kgrp*4 + 0..3]: contiguous 8B per nt.
    short* tp = t8 + (size_t)p * (16384 * 64) + (size_t)row * 64 + kgrp * 4;
    floatx4 accs[4] = {acc0, acc1, acc2, acc3};
    #pragma unroll
    for (int nt = 0; nt < 4; ++nt) {
        short4v v;
        v[0] = f2bf(accs[nt][0]); v[1] = f2bf(accs[nt][1]);
        v[2] = f2bf(accs[nt][2]); v[3] = f2bf(accs[nt][3]);
        *(short4v*)(tp + nt * 16) = v;
    }
}

// k1.5: t = sum of 8 bf16 partials (f32 accumulate). 1M elems / 4 per thread.
__global__ __launch_bounds__(256) void k1_sum(
    const short* __restrict__ t8, short* __restrict__ t) {
    const int i = blockIdx.x * 256 + threadIdx.x;   // 0 .. 262143
    const size_t off = (size_t)i * 4;
    float s0 = 0.f, s1 = 0.f, s2 = 0.f, s3 = 0.f;
    #pragma unroll
    for (int p = 0; p < 8; ++p) {
        short4v v = *(const short4v*)(t8 + (size_t)p * (16384 * 64) + off);
        s0 += bf2f(v[0]); s1 += bf2f(v[1]); s2 += bf2f(v[2]); s3 += bf2f(v[3]);
    }
    short4v r;
    r[0] = f2bf(s0); r[1] = f2bf(s1); r[2] = f2bf(s2); r[3] = f2bf(s3);
    *(short4v*)(t + off) = r;
}

// k2: out = (t @ B) * tw * 2, operand-swapped MFMA, LDS-staged epilogue.
// 16384 blocks x 4 waves: block = 16 rows x 256 cols. LDS 16.4 KB, VGPR 48
// -> __launch_bounds__(256, 8): 8 blocks/CU (131 KB LDS), doubling the waves
// available to hide t/B L2 latency between barrier and store burst (R15 lever:
// k2 is store-bound; TLP is its only latency-hiding mechanism).
__global__ __launch_bounds__(256, 8) void k2_tB(
    const short* __restrict__ t, const float* __restrict__ tw,
    const short* __restrict__ Bbf, float* __restrict__ out) {
    __shared__ float tile[16][257];       // +1 float pad (16.4 KB)

    const int lane = threadIdx.x & 63;
    const int wave = threadIdx.x >> 6;
    const int rg = blockIdx.x >> 4;
    const int cs = blockIdx.x & 15;
    const int rowbase = rg * 16;
    const int colblk = cs * 256;
    const int rrow = lane & 15;
    const int kgrp = lane >> 4;
    const int kofs = kgrp * 8;

    // t fragment (MFMA B-operand): lane holds t[rowbase+rrow][kofs+j]
    const short* t0 = t + (size_t)(rowbase + rrow) * 64 + kofs;
    short8 a0 = *(const short8*)t0;
    short8 a1 = *(const short8*)(t0 + 32);

    // B fragments (MFMA A-operand): Bbf8[(ct*2+ks)*64 + lane], ct = col/16
    const short8* bp = (const short8*)Bbf + (size_t)((colblk + wave * 64) >> 4) * 128 + lane;

    const float w = tw[rowbase + rrow] * 2.0f;

    #pragma unroll
    for (int nt = 0; nt < 4; ++nt) {
        short8 b0 = bp[(nt * 2 + 0) * 64];
        short8 b1 = bp[(nt * 2 + 1) * 64];
        floatx4 acc = {0, 0, 0, 0};
        // swapped: lane holds out[rrow][wave*64 + nt*16 + kgrp*4 + 0..3]
        acc = __builtin_amdgcn_mfma_f32_16x16x32_bf16(b0, a0, acc, 0, 0, 0);
        acc = __builtin_amdgcn_mfma_f32_16x16x32_bf16(b1, a1, acc, 0, 0, 0);
        acc[0] *= w; acc[1] *= w; acc[2] *= w; acc[3] *= w;
        *(floatx4*)&tile[rrow][wave * 64 + nt * 16 + kgrp * 4] = acc;
    }
    __syncthreads();

    // row-linear write-out: wave w -> rows 4w..4w+3; lane l -> row 4w+(l>>4),
    // 16B chunk (l&15)*16B within each 64-float column group q.
    const int orow_i = 4 * wave + (lane >> 4);
    float* orow = out + (size_t)(rowbase + orow_i) * 4096 + colblk;
    #pragma unroll
    for (int q = 0; q < 4; ++q) {
        const int c = q * 64 + rrow * 4;
        floatx4 v = *(const floatx4*)&tile[orow_i][c];
        __builtin_nontemporal_store(v, (floatx4*)(orow + c));
    }
}

extern "C" void kernel_launch(void* const* d_in, const int* in_sizes, int n_in,
                              void* d_out, int out_size, void* d_ws, size_t ws_size,
                              hipStream_t stream) {
    const float* x  = (const float*)d_in[0];   // (8,2048,4096)
    const float* tw = (const float*)d_in[1];   // (8,2048)
    const float* A  = (const float*)d_in[2];   // (4096,64)
    const float* B  = (const float*)d_in[3];   // (64,4096)
    float* out = (float*)d_out;                // (8,2048,4096) fp32

    short* Abf = (short*)d_ws;                 // 512 KB
    short* Bbf = Abf + 262144;                 // 512 KB
    short* t8  = Bbf + 262144;                 // 8 x 16384 x 64 bf16 = 16 MB
    short* t   = t8 + (size_t)8 * 16384 * 64;  // 2 MB

    conv_ab<<<1024, 256, 0, stream>>>(A, B, Abf, Bbf);
    k1_xA<<<dim3(1024, 2), 256, 0, stream>>>(x, tw, Abf, t8);
    k1_sum<<<1024, 256, 0, stream>>>(t8, t);
    k2_tB<<<16384, 256, 0, stream>>>(t, tw, Bbf, out);
}

// Round 17
// 92.895 us; speedup vs baseline: 2.1600x; 1.0001x over previous
//
#include <hip/hip_runtime.h>

typedef short short4v __attribute__((ext_vector_type(4)));
typedef short short8 __attribute__((ext_vector_type(8)));
typedef float floatx4 __attribute__((ext_vector_type(4)));

// Native bf16 conversion: compiler emits packed v_cvt_pk_bf16_f32 (RTNE).
__device__ __forceinline__ short f2bf(float f) {
    __bf16 h = (__bf16)f;
    return __builtin_bit_cast(short, h);
}
__device__ __forceinline__ float bf2f(short s) {
    unsigned u = ((unsigned)(unsigned short)s) << 16;
    return __builtin_bit_cast(float, u);
}

// Convert lora_A (4096x64) and lora_B (64x4096) fp32 -> bf16 in MFMA fragment
// layout for mfma_f32_16x16x32_bf16:
//   lane l holds elem[k][c] with c = l&15, k = 8*(l>>4) + j, j=0..7
__global__ __launch_bounds__(256) void conv_ab(
    const float* __restrict__ A, const float* __restrict__ B,
    short* __restrict__ Abf, short* __restrict__ Bbf) {
    int i = blockIdx.x * 256 + threadIdx.x;   // 0 .. 262143
    int j    = i & 7;
    int lane = (i >> 3) & 63;
    int hi   = i >> 9;                        // A: ks*4+nt ; B: ct*2+ks
    int krow = 8 * (lane >> 4) + j;
    int cc   = lane & 15;
    {   // A fragments
        int ks = hi >> 2, nt = hi & 3;
        Abf[i] = f2bf(A[(size_t)(ks * 32 + krow) * 64 + nt * 16 + cc]);
    }
    {   // B fragments
        int ct = hi >> 1, ks = hi & 1;
        Bbf[i] = f2bf(B[(size_t)(ks * 32 + krow) * 4096 + ct * 16 + cc]);
    }
}

// k1: 8 bf16 split-K partials of t = x @ A (R10 best config: 2-deep rotating
// register pipeline). Grid (1024, 2) x 4 waves; wave w owns rows bx*16..+15,
// ksplit p = by*4+w. Operand-SWAPPED mfma -> lane holds 4 consecutive t-cols
// of ONE row -> direct 8B stores. No LDS, no barriers.
__global__ __launch_bounds__(256, 4) void k1_xA(
    const float* __restrict__ x, const float* __restrict__ tw,
    const short* __restrict__ Abf, short* __restrict__ t8) {
    const int lane = threadIdx.x & 63;
    const int wave = threadIdx.x >> 6;
    const int rowbase = blockIdx.x * 16;
    const int rrow = lane & 15;
    const int kgrp = lane >> 4;
    const int p = blockIdx.y * 4 + wave;      // ksplit 0..7
    const int kbase = p * 512;

    const int row = rowbase + rrow;
    const bool active = (tw[row] != 0.0f);
    const floatx4* xv = (const floatx4*)(x + (size_t)row * 4096 + kbase + kgrp * 8);
    // Abf8[(ksg*4+nt)*64 + lane], ksg = kbase/32 + ks
    const short8* ap = (const short8*)Abf + ((size_t)(kbase >> 5) * 256) + lane;

    floatx4 acc0 = {0,0,0,0}, acc1 = {0,0,0,0}, acc2 = {0,0,0,0}, acc3 = {0,0,0,0};

    floatx4 px[2][2];
    short8  pb[2][4];
    #pragma unroll
    for (int s = 0; s < 2; ++s) {
        px[s][0] = (floatx4){0,0,0,0};
        px[s][1] = (floatx4){0,0,0,0};
        if (active) { px[s][0] = xv[s * 8]; px[s][1] = xv[s * 8 + 1]; }
        pb[s][0] = ap[s * 256 + 0 * 64];
        pb[s][1] = ap[s * 256 + 1 * 64];
        pb[s][2] = ap[s * 256 + 2 * 64];
        pb[s][3] = ap[s * 256 + 3 * 64];
    }

    #pragma unroll
    for (int ks = 0; ks < 16; ++ks) {
        const int s = ks & 1;
        short8 xa;
        xa[0] = f2bf(px[s][0][0]); xa[1] = f2bf(px[s][0][1]);
        xa[2] = f2bf(px[s][0][2]); xa[3] = f2bf(px[s][0][3]);
        xa[4] = f2bf(px[s][1][0]); xa[5] = f2bf(px[s][1][1]);
        xa[6] = f2bf(px[s][1][2]); xa[7] = f2bf(px[s][1][3]);
        short8 b0 = pb[s][0], b1 = pb[s][1], b2 = pb[s][2], b3 = pb[s][3];

        if (ks + 2 < 16) {
            if (active) { px[s][0] = xv[(ks + 2) * 8]; px[s][1] = xv[(ks + 2) * 8 + 1]; }
            pb[s][0] = ap[(ks + 2) * 256 + 0 * 64];
            pb[s][1] = ap[(ks + 2) * 256 + 1 * 64];
            pb[s][2] = ap[(ks + 2) * 256 + 2 * 64];
            pb[s][3] = ap[(ks + 2) * 256 + 3 * 64];
        }

        // swapped: A-matrix fragment as A-operand, x fragment as B-operand.
        // D[m][n] = sum_k A[kbase+k][nt*16+m] * x[rowbase+n][kbase+k]
        acc0 = __builtin_amdgcn_mfma_f32_16x16x32_bf16(b0, xa, acc0, 0, 0, 0);
        acc1 = __builtin_amdgcn_mfma_f32_16x16x32_bf16(b1, xa, acc1, 0, 0, 0);
        acc2 = __builtin_amdgcn_mfma_f32_16x16x32_bf16(b2, xa, acc2, 0, 0, 0);
        acc3 = __builtin_amdgcn_mfma_f32_16x16x32_bf16(b3, xa, acc3, 0, 0, 0);
    }

    // D layout: n = lane&15 (token row), m = 4*kgrp + b (t-col within n-tile)
    // -> lane holds t_p[row][nt*16 + kgrp*4 + 0..3]: contiguous 8B per nt.
    short* tp = t8 + (size_t)p * (16384 * 64) + (size_t)row * 64 + kgrp * 4;
    floatx4 accs[4] = {acc0, acc1, acc2, acc3};
    #pragma unroll
    for (int nt = 0; nt < 4; ++nt) {
        short4v v;
        v[0] = f2bf(accs[nt][0]); v[1] = f2bf(accs[nt][1]);
        v[2] = f2bf(accs[nt][2]); v[3] = f2bf(accs[nt][3]);
        *(short4v*)(tp + nt * 16) = v;
    }
}

// k1.5: t = sum of 8 bf16 partials (f32 accumulate). 1M elems / 4 per thread.
__global__ __launch_bounds__(256) void k1_sum(
    const short* __restrict__ t8, short* __restrict__ t) {
    const int i = blockIdx.x * 256 + threadIdx.x;   // 0 .. 262143
    const size_t off = (size_t)i * 4;
    float s0 = 0.f, s1 = 0.f, s2 = 0.f, s3 = 0.f;
    #pragma unroll
    for (int p = 0; p < 8; ++p) {
        short4v v = *(const short4v*)(t8 + (size_t)p * (16384 * 64) + off);
        s0 += bf2f(v[0]); s1 += bf2f(v[1]); s2 += bf2f(v[2]); s3 += bf2f(v[3]);
    }
    short4v r;
    r[0] = f2bf(s0); r[1] = f2bf(s1); r[2] = f2bf(s2); r[3] = f2bf(s3);
    *(short4v*)(t + off) = r;
}

// k2: out = (t @ B) * tw * 2, operand-swapped MFMA, LDS-staged epilogue.
// 16384 blocks x 4 waves: block = 16 rows x 256 cols. LDS 16.4 KB, VGPR 48
// -> __launch_bounds__(256, 8): 8 blocks/CU (131 KB LDS), doubling the waves
// available to hide t/B L2 latency between barrier and store burst (R15 lever:
// k2 is store-bound; TLP is its only latency-hiding mechanism).
__global__ __launch_bounds__(256, 8) void k2_tB(
    const short* __restrict__ t, const float* __restrict__ tw,
    const short* __restrict__ Bbf, float* __restrict__ out) {
    __shared__ float tile[16][257];       // +1 float pad (16.4 KB)

    const int lane = threadIdx.x & 63;
    const int wave = threadIdx.x >> 6;
    const int rg = blockIdx.x >> 4;
    const int cs = blockIdx.x & 15;
    const int rowbase = rg * 16;
    const int colblk = cs * 256;
    const int rrow = lane & 15;
    const int kgrp = lane >> 4;
    const int kofs = kgrp * 8;

    // t fragment (MFMA B-operand): lane holds t[rowbase+rrow][kofs+j]
    const short* t0 = t + (size_t)(rowbase + rrow) * 64 + kofs;
    short8 a0 = *(const short8*)t0;
    short8 a1 = *(const short8*)(t0 + 32);

    // B fragments (MFMA A-operand): Bbf8[(ct*2+ks)*64 + lane], ct = col/16
    const short8* bp = (const short8*)Bbf + (size_t)((colblk + wave * 64) >> 4) * 128 + lane;

    const float w = tw[rowbase + rrow] * 2.0f;

    #pragma unroll
    for (int nt = 0; nt < 4; ++nt) {
        short8 b0 = bp[(nt * 2 + 0) * 64];
        short8 b1 = bp[(nt * 2 + 1) * 64];
        floatx4 acc = {0, 0, 0, 0};
        // swapped: lane holds out[rrow][wave*64 + nt*16 + kgrp*4 + 0..3]
        acc = __builtin_amdgcn_mfma_f32_16x16x32_bf16(b0, a0, acc, 0, 0, 0);
        acc = __builtin_amdgcn_mfma_f32_16x16x32_bf16(b1, a1, acc, 0, 0, 0);
        acc[0] *= w; acc[1] *= w; acc[2] *= w; acc[3] *= w;
        *(floatx4*)&tile[rrow][wave * 64 + nt * 16 + kgrp * 4] = acc;
    }
    __syncthreads();

    // row-linear write-out: wave w -> rows 4w..4w+3; lane l -> row 4w+(l>>4),
    // 16B chunk (l&15)*16B within each 64-float column group q.
    const int orow_i = 4 * wave + (lane >> 4);
    float* orow = out + (size_t)(rowbase + orow_i) * 4096 + colblk;
    #pragma unroll
    for (int q = 0; q < 4; ++q) {
        const int c = q * 64 + rrow * 4;
        floatx4 v = *(const floatx4*)&tile[orow_i][c];
        __builtin_nontemporal_store(v, (floatx4*)(orow + c));
    }
}

extern "C" void kernel_launch(void* const* d_in, const int* in_sizes, int n_in,
                              void* d_out, int out_size, void* d_ws, size_t ws_size,
                              hipStream_t stream) {
    const float* x  = (const float*)d_in[0];   // (8,2048,4096)
    const float* tw = (const float*)d_in[1];   // (8,2048)
    const float* A  = (const float*)d_in[2];   // (4096,64)
    const float* B  = (const float*)d_in[3];   // (64,4096)
    float* out = (float*)d_out;                // (8,2048,4096) fp32

    short* Abf = (short*)d_ws;                 // 512 KB
    short* Bbf = Abf + 262144;                 // 512 KB
    short* t8  = Bbf + 262144;                 // 8 x 16384 x 64 bf16 = 16 MB
    short* t   = t8 + (size_t)8 * 16384 * 64;  // 2 MB

    conv_ab<<<1024, 256, 0, stream>>>(A, B, Abf, Bbf);
    k1_xA<<<dim3(1024, 2), 256, 0, stream>>>(x, tw, Abf, t8);
    k1_sum<<<1024, 256, 0, stream>>>(t8, t);
    k2_tB<<<16384, 256, 0, stream>>>(t, tw, Bbf, out);
}